// Round 12
// baseline (670.111 us; speedup 1.0000x reference)
//
#include <hip/hip_runtime.h>

#define HID 128
#define ASPITCH 132   // padded A-tile pitch for k_gemm0 (round-5 proven)
#define BM 64

// ---------------- CSR build ----------------

__global__ __launch_bounds__(256) void k_count(const int* __restrict__ ei, int E,
                                               int* __restrict__ deg) {
    int e = blockIdx.x * 256 + threadIdx.x;
    if (e < E) atomicAdd(&deg[ei[E + e]], 1);   // row 1 of edge_index = dst
}

__global__ __launch_bounds__(256) void k_scan1(const int* __restrict__ deg,
                                               int* __restrict__ rowptr,
                                               int* __restrict__ partial, int n) {
    __shared__ int s[256];
    int tid = threadIdx.x;
    int i = blockIdx.x * 256 + tid;
    int v = (i < n) ? deg[i] : 0;
    s[tid] = v;
    __syncthreads();
    for (int off = 1; off < 256; off <<= 1) {
        int t = (tid >= off) ? s[tid - off] : 0;
        __syncthreads();
        s[tid] += t;
        __syncthreads();
    }
    if (i < n) rowptr[i] = s[tid] - v;           // block-local exclusive
    if (tid == 255) partial[blockIdx.x] = s[255];
}

__global__ __launch_bounds__(256) void k_scan2(int* __restrict__ partial, int nb) {
    __shared__ int s[256];
    int tid = threadIdx.x;
    int v = (tid < nb) ? partial[tid] : 0;
    s[tid] = v;
    __syncthreads();
    for (int off = 1; off < 256; off <<= 1) {
        int t = (tid >= off) ? s[tid - off] : 0;
        __syncthreads();
        s[tid] += t;
        __syncthreads();
    }
    if (tid < nb) partial[tid] = s[tid] - v;     // exclusive over block sums
}

__global__ __launch_bounds__(256) void k_scan3(int* __restrict__ rowptr,
                                               const int* __restrict__ partial,
                                               int n, int E) {
    int i = blockIdx.x * 256 + threadIdx.x;
    if (i < n) rowptr[i] += partial[blockIdx.x];
    if (i == 0) rowptr[n] = E;
}

__global__ __launch_bounds__(256) void k_dis(const int* __restrict__ deg,
                                             float* __restrict__ dis, int n) {
    int i = blockIdx.x * 256 + threadIdx.x;
    if (i < n) dis[i] = 1.0f / sqrtf((float)(deg[i] + 1));  // +1 self-loop
}

__global__ __launch_bounds__(256) void k_fill(const int* __restrict__ ei, int E,
                                              const int* __restrict__ rowptr,
                                              int* __restrict__ cursor,
                                              int* __restrict__ col) {
    int e = blockIdx.x * 256 + threadIdx.x;
    if (e < E) {
        int d = ei[E + e];
        int p = atomicAdd(&cursor[d], 1);
        col[rowptr[d] + p] = ei[e];
    }
}

// ---------------- compute kernels ----------------

// U[i,:] = dis[i] * (A[i,:] @ W)   — first-layer GEMM (round-5 version, proven).
__global__ __launch_bounds__(256, 3) void k_gemm0(const float* __restrict__ A,
                                                  const float* __restrict__ W,
                                                  const float* __restrict__ dis,
                                                  float* __restrict__ T, int n) {
    __shared__ float As[BM * ASPITCH];
    int r0 = blockIdx.x * BM;
    int tid = threadIdx.x;
    int rows = n - r0; if (rows > BM) rows = BM;
    {
        const float4* A4 = (const float4*)(A + (size_t)r0 * HID);
        int tot = rows * (HID / 4);
        for (int i = tid; i < tot; i += 256) {
            int row = i >> 5, c = (i & 31) << 2;
            *(float4*)&As[row * ASPITCH + c] = A4[i];
        }
    }
    __syncthreads();

    int tx = tid & 31, ty = tid >> 5;
    int rr0 = ty * 8;
    const float4* W4 = (const float4*)W;

    float acc[8][4];
    #pragma unroll
    for (int r = 0; r < 8; ++r) { acc[r][0]=0.f; acc[r][1]=0.f; acc[r][2]=0.f; acc[r][3]=0.f; }

    float4 wa0 = W4[0 * 32 + tx];
    float4 wa1 = W4[1 * 32 + tx];
    float4 wa2 = W4[2 * 32 + tx];
    float4 wa3 = W4[3 * 32 + tx];
    float4 wb0, wb1, wb2, wb3;

    #pragma unroll 1
    for (int k = 0; k < HID; k += 8) {
        wb0 = W4[(k + 4) * 32 + tx];
        wb1 = W4[(k + 5) * 32 + tx];
        wb2 = W4[(k + 6) * 32 + tx];
        wb3 = W4[(k + 7) * 32 + tx];
        #pragma unroll
        for (int r = 0; r < 8; ++r) {
            float4 a = *(const float4*)&As[(rr0 + r) * ASPITCH + k];
            acc[r][0] = fmaf(a.x, wa0.x, acc[r][0]);
            acc[r][1] = fmaf(a.x, wa0.y, acc[r][1]);
            acc[r][2] = fmaf(a.x, wa0.z, acc[r][2]);
            acc[r][3] = fmaf(a.x, wa0.w, acc[r][3]);
            acc[r][0] = fmaf(a.y, wa1.x, acc[r][0]);
            acc[r][1] = fmaf(a.y, wa1.y, acc[r][1]);
            acc[r][2] = fmaf(a.y, wa1.z, acc[r][2]);
            acc[r][3] = fmaf(a.y, wa1.w, acc[r][3]);
            acc[r][0] = fmaf(a.z, wa2.x, acc[r][0]);
            acc[r][1] = fmaf(a.z, wa2.y, acc[r][1]);
            acc[r][2] = fmaf(a.z, wa2.z, acc[r][2]);
            acc[r][3] = fmaf(a.z, wa2.w, acc[r][3]);
            acc[r][0] = fmaf(a.w, wa3.x, acc[r][0]);
            acc[r][1] = fmaf(a.w, wa3.y, acc[r][1]);
            acc[r][2] = fmaf(a.w, wa3.z, acc[r][2]);
            acc[r][3] = fmaf(a.w, wa3.w, acc[r][3]);
        }
        if (k + 8 < HID) {
            wa0 = W4[(k + 8)  * 32 + tx];
            wa1 = W4[(k + 9)  * 32 + tx];
            wa2 = W4[(k + 10) * 32 + tx];
            wa3 = W4[(k + 11) * 32 + tx];
        }
        #pragma unroll
        for (int r = 0; r < 8; ++r) {
            float4 a = *(const float4*)&As[(rr0 + r) * ASPITCH + k + 4];
            acc[r][0] = fmaf(a.x, wb0.x, acc[r][0]);
            acc[r][1] = fmaf(a.x, wb0.y, acc[r][1]);
            acc[r][2] = fmaf(a.x, wb0.z, acc[r][2]);
            acc[r][3] = fmaf(a.x, wb0.w, acc[r][3]);
            acc[r][0] = fmaf(a.y, wb1.x, acc[r][0]);
            acc[r][1] = fmaf(a.y, wb1.y, acc[r][1]);
            acc[r][2] = fmaf(a.y, wb1.z, acc[r][2]);
            acc[r][3] = fmaf(a.y, wb1.w, acc[r][3]);
            acc[r][0] = fmaf(a.z, wb2.x, acc[r][0]);
            acc[r][1] = fmaf(a.z, wb2.y, acc[r][1]);
            acc[r][2] = fmaf(a.z, wb2.z, acc[r][2]);
            acc[r][3] = fmaf(a.z, wb2.w, acc[r][3]);
            acc[r][0] = fmaf(a.w, wb3.x, acc[r][0]);
            acc[r][1] = fmaf(a.w, wb3.y, acc[r][1]);
            acc[r][2] = fmaf(a.w, wb3.z, acc[r][2]);
            acc[r][3] = fmaf(a.w, wb3.w, acc[r][3]);
        }
    }

    int c0 = tx * 4;
    #pragma unroll
    for (int r = 0; r < 8; ++r) {
        int row = rr0 + r;
        if (row < rows) {
            float d = dis[r0 + row];
            float4 o = make_float4(acc[r][0] * d, acc[r][1] * d, acc[r][2] * d, acc[r][3] * d);
            *(float4*)&T[(size_t)(r0 + row) * HID + c0] = o;
        }
    }
}

// Fused agg+gemm with FEATURE-SLICED gather (r8 structure otherwise).
// Phase A: 8 passes over 16-float feature slices. Per-pass live gather set =
// n*64B = 3.2 MB < 4 MB per-XCD L2, so capacity misses (57% miss rate at full
// 25.6 MB working set) become compulsory-only. Blocks run near-lockstep
// (r7-r11 evidence), so all CUs share the same slice window concurrently.
// Wave layout: 16 rowslots x 4 flanes (float4). Wave w writes S rows
// 16w..16w+15; phase B's half-waves 2w,2w+1 read exactly those rows ->
// wave-private S, no barrier (r8-validated ordering argument).
__global__ __launch_bounds__(256, 3) void k_aggemm(const float* __restrict__ Uin,
                                                   const float* __restrict__ W,
                                                   const float* __restrict__ b,
                                                   const float* __restrict__ dis,
                                                   const int* __restrict__ rowptr,
                                                   const int* __restrict__ col,
                                                   float* __restrict__ Uout, int n) {
    __shared__ float S[BM * HID];   // 32 KB
    int r0 = blockIdx.x * BM;
    int tid = threadIdx.x;

    // ---- phase A: feature-sliced gather ----
    {
        int w = tid >> 6;            // wave 0..3
        int lane = tid & 63;
        int rowslot = lane >> 2;     // 0..15
        int flane = lane & 3;        // 0..3 -> float4 within 16-float slice
        int lrow = w * 16 + rowslot; // 0..63 within tile
        int row = r0 + lrow;
        bool rv = row < n;
        int e0 = 0, e1 = 0;
        float dd = 0.f;
        if (rv) { e0 = rowptr[row]; e1 = rowptr[row + 1]; dd = dis[row]; }

        #pragma unroll 1
        for (int s = 0; s < 8; ++s) {
            int fo = s * 16 + flane * 4;
            float4 bb = *(const float4*)&b[fo];
            float4 acc = make_float4(0.f, 0.f, 0.f, 0.f);
            float4 acc2 = make_float4(0.f, 0.f, 0.f, 0.f);
            if (rv) acc = *(const float4*)&Uin[(size_t)row * HID + fo];  // self
            int e = e0;
            while (__any(e < e1)) {
                bool m0 = e + 0 < e1, m1 = e + 1 < e1, m2 = e + 2 < e1, m3 = e + 3 < e1;
                int j0 = col[m0 ? e + 0 : 0];
                int j1 = col[m1 ? e + 1 : 0];
                int j2 = col[m2 ? e + 2 : 0];
                int j3 = col[m3 ? e + 3 : 0];
                float4 v0 = *(const float4*)&Uin[(size_t)j0 * HID + fo];
                float4 v1 = *(const float4*)&Uin[(size_t)j1 * HID + fo];
                float4 v2 = *(const float4*)&Uin[(size_t)j2 * HID + fo];
                float4 v3 = *(const float4*)&Uin[(size_t)j3 * HID + fo];
                float4 z = make_float4(0.f, 0.f, 0.f, 0.f);
                float4 w0_ = m0 ? v0 : z;
                float4 w1_ = m1 ? v1 : z;
                float4 w2_ = m2 ? v2 : z;
                float4 w3_ = m3 ? v3 : z;
                acc.x  += w0_.x + w1_.x;
                acc.y  += w0_.y + w1_.y;
                acc.z  += w0_.z + w1_.z;
                acc.w  += w0_.w + w1_.w;
                acc2.x += w2_.x + w3_.x;
                acc2.y += w2_.y + w3_.y;
                acc2.z += w2_.z + w3_.z;
                acc2.w += w2_.w + w3_.w;
                e += 4;
            }
            float4 h = make_float4(0.f, 0.f, 0.f, 0.f);
            if (rv) {
                h.x = fmaxf(fmaf(dd, acc.x + acc2.x, bb.x), 0.0f);
                h.y = fmaxf(fmaf(dd, acc.y + acc2.y, bb.y), 0.0f);
                h.z = fmaxf(fmaf(dd, acc.z + acc2.z, bb.z), 0.0f);
                h.w = fmaxf(fmaf(dd, acc.w + acc2.w, bb.w), 0.0f);
            }
            *(float4*)&S[lrow * HID + fo] = h;
        }
    }
    // NO __syncthreads(): S rows 16w..16w+15 written by wave w, read by the
    // same wave's half-waves in phase B — same-wave LDS ordering suffices.

    // ---- phase B: S @ W, 8r x 4c, register ping-pong W prefetch (r8 body) ----
    int tx = tid & 31, ty = tid >> 5;
    int rr0 = ty * 8;
    const float4* W4 = (const float4*)W;

    float acc[8][4];
    #pragma unroll
    for (int r = 0; r < 8; ++r) { acc[r][0]=0.f; acc[r][1]=0.f; acc[r][2]=0.f; acc[r][3]=0.f; }

    float4 wa0 = W4[0 * 32 + tx];
    float4 wa1 = W4[1 * 32 + tx];
    float4 wa2 = W4[2 * 32 + tx];
    float4 wa3 = W4[3 * 32 + tx];
    float4 wb0, wb1, wb2, wb3;

    #pragma unroll 1
    for (int k = 0; k < HID; k += 8) {
        wb0 = W4[(k + 4) * 32 + tx];
        wb1 = W4[(k + 5) * 32 + tx];
        wb2 = W4[(k + 6) * 32 + tx];
        wb3 = W4[(k + 7) * 32 + tx];
        #pragma unroll
        for (int r = 0; r < 8; ++r) {
            float4 a = *(const float4*)&S[(rr0 + r) * HID + k];
            acc[r][0] = fmaf(a.x, wa0.x, acc[r][0]);
            acc[r][1] = fmaf(a.x, wa0.y, acc[r][1]);
            acc[r][2] = fmaf(a.x, wa0.z, acc[r][2]);
            acc[r][3] = fmaf(a.x, wa0.w, acc[r][3]);
            acc[r][0] = fmaf(a.y, wa1.x, acc[r][0]);
            acc[r][1] = fmaf(a.y, wa1.y, acc[r][1]);
            acc[r][2] = fmaf(a.y, wa1.z, acc[r][2]);
            acc[r][3] = fmaf(a.y, wa1.w, acc[r][3]);
            acc[r][0] = fmaf(a.z, wa2.x, acc[r][0]);
            acc[r][1] = fmaf(a.z, wa2.y, acc[r][1]);
            acc[r][2] = fmaf(a.z, wa2.z, acc[r][2]);
            acc[r][3] = fmaf(a.z, wa2.w, acc[r][3]);
            acc[r][0] = fmaf(a.w, wa3.x, acc[r][0]);
            acc[r][1] = fmaf(a.w, wa3.y, acc[r][1]);
            acc[r][2] = fmaf(a.w, wa3.z, acc[r][2]);
            acc[r][3] = fmaf(a.w, wa3.w, acc[r][3]);
        }
        if (k + 8 < HID) {
            wa0 = W4[(k + 8)  * 32 + tx];
            wa1 = W4[(k + 9)  * 32 + tx];
            wa2 = W4[(k + 10) * 32 + tx];
            wa3 = W4[(k + 11) * 32 + tx];
        }
        #pragma unroll
        for (int r = 0; r < 8; ++r) {
            float4 a = *(const float4*)&S[(rr0 + r) * HID + k + 4];
            acc[r][0] = fmaf(a.x, wb0.x, acc[r][0]);
            acc[r][1] = fmaf(a.x, wb0.y, acc[r][1]);
            acc[r][2] = fmaf(a.x, wb0.z, acc[r][2]);
            acc[r][3] = fmaf(a.x, wb0.w, acc[r][3]);
            acc[r][0] = fmaf(a.y, wb1.x, acc[r][0]);
            acc[r][1] = fmaf(a.y, wb1.y, acc[r][1]);
            acc[r][2] = fmaf(a.y, wb1.z, acc[r][2]);
            acc[r][3] = fmaf(a.y, wb1.w, acc[r][3]);
            acc[r][0] = fmaf(a.z, wb2.x, acc[r][0]);
            acc[r][1] = fmaf(a.z, wb2.y, acc[r][1]);
            acc[r][2] = fmaf(a.z, wb2.z, acc[r][2]);
            acc[r][3] = fmaf(a.z, wb2.w, acc[r][3]);
            acc[r][0] = fmaf(a.w, wb3.x, acc[r][0]);
            acc[r][1] = fmaf(a.w, wb3.y, acc[r][1]);
            acc[r][2] = fmaf(a.w, wb3.z, acc[r][2]);
            acc[r][3] = fmaf(a.w, wb3.w, acc[r][3]);
        }
    }

    int rows = n - r0; if (rows > BM) rows = BM;
    int c0 = tx * 4;
    #pragma unroll
    for (int r = 0; r < 8; ++r) {
        int row = rr0 + r;
        if (row < rows) {
            float d = dis[r0 + row];
            float4 o = make_float4(acc[r][0] * d, acc[r][1] * d, acc[r][2] * d, acc[r][3] * d);
            *(float4*)&Uout[(size_t)(r0 + row) * HID + c0] = o;
        }
    }
}

// Last layer: aggregate + bias + relu + dot with lin_w, all in registers.
// half-wave per node.
__global__ __launch_bounds__(256) void k_agglin(const float* __restrict__ Uin,
                                                const float* __restrict__ b,
                                                const float* __restrict__ dis,
                                                const int* __restrict__ rowptr,
                                                const int* __restrict__ col,
                                                const float* __restrict__ lw,
                                                const float* __restrict__ lb,
                                                float* __restrict__ out, int n) {
    int node = (blockIdx.x * 256 + threadIdx.x) >> 5;
    int lane = threadIdx.x & 31;
    if (node >= n) return;
    size_t foff = (size_t)(lane * 4);
    float4 acc = *(const float4*)&Uin[(size_t)node * HID + foff];
    float4 acc2 = make_float4(0.f, 0.f, 0.f, 0.f);
    int e = rowptr[node], e1 = rowptr[node + 1];
    for (; e + 8 <= e1; e += 8) {
        int j0 = col[e + 0];
        int j1 = col[e + 1];
        int j2 = col[e + 2];
        int j3 = col[e + 3];
        int j4 = col[e + 4];
        int j5 = col[e + 5];
        int j6 = col[e + 6];
        int j7 = col[e + 7];
        float4 v0 = *(const float4*)&Uin[(size_t)j0 * HID + foff];
        float4 v1 = *(const float4*)&Uin[(size_t)j1 * HID + foff];
        float4 v2 = *(const float4*)&Uin[(size_t)j2 * HID + foff];
        float4 v3 = *(const float4*)&Uin[(size_t)j3 * HID + foff];
        float4 v4 = *(const float4*)&Uin[(size_t)j4 * HID + foff];
        float4 v5 = *(const float4*)&Uin[(size_t)j5 * HID + foff];
        float4 v6 = *(const float4*)&Uin[(size_t)j6 * HID + foff];
        float4 v7 = *(const float4*)&Uin[(size_t)j7 * HID + foff];
        acc.x  += (v0.x + v1.x) + (v2.x + v3.x);
        acc.y  += (v0.y + v1.y) + (v2.y + v3.y);
        acc.z  += (v0.z + v1.z) + (v2.z + v3.z);
        acc.w  += (v0.w + v1.w) + (v2.w + v3.w);
        acc2.x += (v4.x + v5.x) + (v6.x + v7.x);
        acc2.y += (v4.y + v5.y) + (v6.y + v7.y);
        acc2.z += (v4.z + v5.z) + (v6.z + v7.z);
        acc2.w += (v4.w + v5.w) + (v6.w + v7.w);
    }
    for (; e + 2 <= e1; e += 2) {
        int j0 = col[e + 0];
        int j1 = col[e + 1];
        float4 v0 = *(const float4*)&Uin[(size_t)j0 * HID + foff];
        float4 v1 = *(const float4*)&Uin[(size_t)j1 * HID + foff];
        acc.x  += v0.x; acc.y  += v0.y; acc.z  += v0.z; acc.w  += v0.w;
        acc2.x += v1.x; acc2.y += v1.y; acc2.z += v1.z; acc2.w += v1.w;
    }
    if (e < e1) {
        int j = col[e];
        float4 v = *(const float4*)&Uin[(size_t)j * HID + foff];
        acc.x += v.x; acc.y += v.y; acc.z += v.z; acc.w += v.w;
    }
    float d = dis[node];
    float4 bb = *(const float4*)&b[lane * 4];
    float4 h;
    h.x = fmaxf(fmaf(d, acc.x + acc2.x, bb.x), 0.0f);
    h.y = fmaxf(fmaf(d, acc.y + acc2.y, bb.y), 0.0f);
    h.z = fmaxf(fmaf(d, acc.z + acc2.z, bb.z), 0.0f);
    h.w = fmaxf(fmaf(d, acc.w + acc2.w, bb.w), 0.0f);
    float4 ww = *(const float4*)&lw[lane * 4];
    float s = h.x * ww.x + h.y * ww.y + h.z * ww.z + h.w * ww.w;
    #pragma unroll
    for (int o = 16; o > 0; o >>= 1) s += __shfl_down(s, o, 64);  // stays within half
    if (lane == 0) out[node] = s + lb[0];
}

// ---------------- launch ----------------

extern "C" void kernel_launch(void* const* d_in, const int* in_sizes, int n_in,
                              void* d_out, int out_size, void* d_ws, size_t ws_size,
                              hipStream_t stream) {
    const float* x     = (const float*)d_in[0];
    const int*   ei    = (const int*)d_in[1];
    const float* Ws    = (const float*)d_in[2];
    const float* bs    = (const float*)d_in[3];
    const float* lin_w = (const float*)d_in[4];
    const float* lin_b = (const float*)d_in[5];
    float* out = (float*)d_out;

    int n = in_sizes[0] / HID;           // 50000
    int E = in_sizes[1] / 2;             // 600000
    int L = in_sizes[2] / (HID * HID);   // 7

    char* ws = (char*)d_ws;
    size_t off = 0;
    auto alloc = [&](size_t bytes) -> void* {
        void* p = ws + off;
        off += (bytes + 255) & ~(size_t)255;
        return p;
    };
    int*   deg     = (int*)alloc((size_t)n * 4);
    int*   cursor  = (int*)alloc((size_t)n * 4);
    int*   rowptr  = (int*)alloc((size_t)(n + 1) * 4);
    int*   partial = (int*)alloc(1024);
    float* dis     = (float*)alloc((size_t)n * 4);
    int*   col     = (int*)alloc((size_t)E * 4);
    float* ubuf0   = (float*)alloc((size_t)n * HID * 4);
    float* ubuf1   = (float*)alloc((size_t)n * HID * 4);
    (void)ws_size;

    hipMemsetAsync(deg, 0, (size_t)n * 4, stream);
    hipMemsetAsync(cursor, 0, (size_t)n * 4, stream);

    int eb = (E + 255) / 256;
    int nb = (n + 255) / 256;
    k_count<<<eb, 256, 0, stream>>>(ei, E, deg);
    k_scan1<<<nb, 256, 0, stream>>>(deg, rowptr, partial, n);
    k_scan2<<<1, 256, 0, stream>>>(partial, nb);
    k_scan3<<<nb, 256, 0, stream>>>(rowptr, partial, n, E);
    k_dis<<<nb, 256, 0, stream>>>(deg, dis, n);
    k_fill<<<eb, 256, 0, stream>>>(ei, E, rowptr, cursor, col);

    int gb = (n + BM - 1) / BM;  // 782
    int hb = (n + 7) / 8;

    // U_0 = dis * (x @ W0)
    k_gemm0<<<gb, 256, 0, stream>>>(x, Ws, dis, ubuf0, n);

    // U_{i+1} = dis * (relu(dis*agg(U_i) + b_i) @ W_{i+1})   for i = 0..L-2
    float* uin = ubuf0;
    float* uout = ubuf1;
    for (int i = 0; i + 1 < L; ++i) {
        k_aggemm<<<gb, 256, 0, stream>>>(uin, Ws + (size_t)(i + 1) * HID * HID,
                                         bs + (size_t)i * HID, dis, rowptr, col,
                                         uout, n);
        float* t = uin; uin = uout; uout = t;
    }

    // out = relu(dis*agg(U_{L-1}) + b_{L-1}) @ lin_w + lin_b
    k_agglin<<<hb, 256, 0, stream>>>(uin, bs + (size_t)(L - 1) * HID, dis,
                                     rowptr, col, lin_w, lin_b, out, n);
}

// Round 13
// 615.788 us; speedup vs baseline: 1.0882x; 1.0882x over previous
//
#include <hip/hip_runtime.h>

#define HID 128
#define ASPITCH 132   // padded pitch: row stride 132 floats -> banks shift 4/row
#define BM 64

// 8 FMAs: acc[R][0..7] += AV * {W0,W1}
#define FMA8(AV, W0, W1, R)                        \
    acc[R][0] = fmaf(AV, W0.x, acc[R][0]);         \
    acc[R][1] = fmaf(AV, W0.y, acc[R][1]);         \
    acc[R][2] = fmaf(AV, W0.z, acc[R][2]);         \
    acc[R][3] = fmaf(AV, W0.w, acc[R][3]);         \
    acc[R][4] = fmaf(AV, W1.x, acc[R][4]);         \
    acc[R][5] = fmaf(AV, W1.y, acc[R][5]);         \
    acc[R][6] = fmaf(AV, W1.z, acc[R][6]);         \
    acc[R][7] = fmaf(AV, W1.w, acc[R][7]);

// ---------------- CSR build ----------------

__global__ __launch_bounds__(256) void k_count(const int* __restrict__ ei, int E,
                                               int* __restrict__ deg) {
    int e = blockIdx.x * 256 + threadIdx.x;
    if (e < E) atomicAdd(&deg[ei[E + e]], 1);   // row 1 of edge_index = dst
}

__global__ __launch_bounds__(256) void k_scan1(const int* __restrict__ deg,
                                               int* __restrict__ rowptr,
                                               int* __restrict__ partial, int n) {
    __shared__ int s[256];
    int tid = threadIdx.x;
    int i = blockIdx.x * 256 + tid;
    int v = (i < n) ? deg[i] : 0;
    s[tid] = v;
    __syncthreads();
    for (int off = 1; off < 256; off <<= 1) {
        int t = (tid >= off) ? s[tid - off] : 0;
        __syncthreads();
        s[tid] += t;
        __syncthreads();
    }
    if (i < n) rowptr[i] = s[tid] - v;           // block-local exclusive
    if (tid == 255) partial[blockIdx.x] = s[255];
}

__global__ __launch_bounds__(256) void k_scan2(int* __restrict__ partial, int nb) {
    __shared__ int s[256];
    int tid = threadIdx.x;
    int v = (tid < nb) ? partial[tid] : 0;
    s[tid] = v;
    __syncthreads();
    for (int off = 1; off < 256; off <<= 1) {
        int t = (tid >= off) ? s[tid - off] : 0;
        __syncthreads();
        s[tid] += t;
        __syncthreads();
    }
    if (tid < nb) partial[tid] = s[tid] - v;     // exclusive over block sums
}

__global__ __launch_bounds__(256) void k_scan3(int* __restrict__ rowptr,
                                               const int* __restrict__ partial,
                                               int n, int E) {
    int i = blockIdx.x * 256 + threadIdx.x;
    if (i < n) rowptr[i] += partial[blockIdx.x];
    if (i == 0) rowptr[n] = E;
}

__global__ __launch_bounds__(256) void k_dis(const int* __restrict__ deg,
                                             float* __restrict__ dis, int n) {
    int i = blockIdx.x * 256 + threadIdx.x;
    if (i < n) dis[i] = 1.0f / sqrtf((float)(deg[i] + 1));  // +1 self-loop
}

__global__ __launch_bounds__(256) void k_fill(const int* __restrict__ ei, int E,
                                              const int* __restrict__ rowptr,
                                              int* __restrict__ cursor,
                                              int* __restrict__ col) {
    int e = blockIdx.x * 256 + threadIdx.x;
    if (e < E) {
        int d = ei[E + e];
        int p = atomicAdd(&cursor[d], 1);
        col[rowptr[d] + p] = ei[e];
    }
}

// ---------------- compute kernels ----------------

// U[i,:] = dis[i] * (A[i,:] @ W) — 4r x 8c thread tile (16 col-groups x 16
// row-groups). Halves LDS b128 reads per FMA vs the 8r x 4c tile (each b128
// now feeds 32 FMAs): the LDS pipe was the B-structure's binding term
// (~12 cyc/instr x 256 reads x 12 waves/CU ≈ 15.6 us > 10.4 us FMA floor).
// W ping-pong at 2-krow granularity keeps VGPR ~100 (< 128 occupancy cliff).
__global__ __launch_bounds__(256, 3) void k_gemm0(const float* __restrict__ A,
                                                  const float* __restrict__ W,
                                                  const float* __restrict__ dis,
                                                  float* __restrict__ T, int n) {
    __shared__ float As[BM * ASPITCH];
    int r0 = blockIdx.x * BM;
    int tid = threadIdx.x;
    int rows = n - r0; if (rows > BM) rows = BM;
    {
        const float4* A4 = (const float4*)(A + (size_t)r0 * HID);
        int tot = rows * (HID / 4);
        for (int i = tid; i < tot; i += 256) {
            int row = i >> 5, c = (i & 31) << 2;
            *(float4*)&As[row * ASPITCH + c] = A4[i];
        }
    }
    __syncthreads();

    int tx = tid & 15, ty = tid >> 4;    // 16 col-groups x 16 row-groups
    int rr0 = ty * 4, c0 = tx * 8;
    const float4* W4 = (const float4*)W; // 32 float4 per k-row; this thread: tx*2, tx*2+1

    float acc[4][8];
    #pragma unroll
    for (int r = 0; r < 4; ++r)
        #pragma unroll
        for (int c = 0; c < 8; ++c) acc[r][c] = 0.0f;

    // preload k-rows 0,1
    float4 wa00 = W4[0 * 32 + tx * 2], wa01 = W4[0 * 32 + tx * 2 + 1];
    float4 wa10 = W4[1 * 32 + tx * 2], wa11 = W4[1 * 32 + tx * 2 + 1];
    float4 wb00, wb01, wb10, wb11;

    #pragma unroll 1
    for (int k = 0; k < HID; k += 4) {
        float4 a0 = *(const float4*)&As[(rr0 + 0) * ASPITCH + k];
        float4 a1 = *(const float4*)&As[(rr0 + 1) * ASPITCH + k];
        float4 a2 = *(const float4*)&As[(rr0 + 2) * ASPITCH + k];
        float4 a3 = *(const float4*)&As[(rr0 + 3) * ASPITCH + k];
        // prefetch k-rows k+2, k+3
        wb00 = W4[(k + 2) * 32 + tx * 2]; wb01 = W4[(k + 2) * 32 + tx * 2 + 1];
        wb10 = W4[(k + 3) * 32 + tx * 2]; wb11 = W4[(k + 3) * 32 + tx * 2 + 1];
        FMA8(a0.x, wa00, wa01, 0) FMA8(a1.x, wa00, wa01, 1)
        FMA8(a2.x, wa00, wa01, 2) FMA8(a3.x, wa00, wa01, 3)
        FMA8(a0.y, wa10, wa11, 0) FMA8(a1.y, wa10, wa11, 1)
        FMA8(a2.y, wa10, wa11, 2) FMA8(a3.y, wa10, wa11, 3)
        // prefetch k-rows k+4, k+5
        if (k + 4 < HID) {
            wa00 = W4[(k + 4) * 32 + tx * 2]; wa01 = W4[(k + 4) * 32 + tx * 2 + 1];
            wa10 = W4[(k + 5) * 32 + tx * 2]; wa11 = W4[(k + 5) * 32 + tx * 2 + 1];
        }
        FMA8(a0.z, wb00, wb01, 0) FMA8(a1.z, wb00, wb01, 1)
        FMA8(a2.z, wb00, wb01, 2) FMA8(a3.z, wb00, wb01, 3)
        FMA8(a0.w, wb10, wb11, 0) FMA8(a1.w, wb10, wb11, 1)
        FMA8(a2.w, wb10, wb11, 2) FMA8(a3.w, wb10, wb11, 3)
    }

    #pragma unroll
    for (int r = 0; r < 4; ++r) {
        int row = rr0 + r;
        if (row < rows) {
            float d = dis[r0 + row];
            float4 o0 = make_float4(acc[r][0] * d, acc[r][1] * d, acc[r][2] * d, acc[r][3] * d);
            float4 o1 = make_float4(acc[r][4] * d, acc[r][5] * d, acc[r][6] * d, acc[r][7] * d);
            *(float4*)&T[(size_t)(r0 + row) * HID + c0] = o0;
            *(float4*)&T[(size_t)(r0 + row) * HID + c0 + 4] = o1;
        }
    }
}

// Fused agg+gemm: phase A identical to r8 (best measured); phase B uses the
// 4r x 8c tile. Privacy: A's half-wave hw (tid>>5) writes S rows 8hw..8hw+7;
// B's thread (ty=tid>>4 = 2hw or 2hw+1) reads rows 4ty..4ty+3 — a subset of
// the SAME half-wave's rows -> no barrier needed (r8-validated ordering).
// S pitch 132 keeps B's 4-address reads 2-way bank-aliased (free, m136).
__global__ __launch_bounds__(256, 3) void k_aggemm(const float* __restrict__ Uin,
                                                   const float* __restrict__ W,
                                                   const float* __restrict__ b,
                                                   const float* __restrict__ dis,
                                                   const int* __restrict__ rowptr,
                                                   const int* __restrict__ col,
                                                   float* __restrict__ Uout, int n) {
    __shared__ float S[BM * ASPITCH];   // ~33.8 KB
    int r0 = blockIdx.x * BM;
    int tid = threadIdx.x;
    int hw = tid >> 5, lane = tid & 31;
    size_t foff = (size_t)(lane * 4);
    float4 bb = *(const float4*)&b[lane * 4];

    // ---- phase A: aggregate 8 rows per half-wave (r8 body, S pitch 132) ----
    #pragma unroll 1
    for (int rr = 0; rr < 8; ++rr) {
        int row = r0 + hw * 8 + rr;
        float4 ga = make_float4(0.f, 0.f, 0.f, 0.f);
        if (row < n) {
            ga = *(const float4*)&Uin[(size_t)row * HID + foff];   // self (pre-scaled)
            float4 ga2 = make_float4(0.f, 0.f, 0.f, 0.f);
            int e = rowptr[row], e1 = rowptr[row + 1];
            for (; e + 8 <= e1; e += 8) {
                int j0 = col[e + 0];
                int j1 = col[e + 1];
                int j2 = col[e + 2];
                int j3 = col[e + 3];
                int j4 = col[e + 4];
                int j5 = col[e + 5];
                int j6 = col[e + 6];
                int j7 = col[e + 7];
                float4 v0 = *(const float4*)&Uin[(size_t)j0 * HID + foff];
                float4 v1 = *(const float4*)&Uin[(size_t)j1 * HID + foff];
                float4 v2 = *(const float4*)&Uin[(size_t)j2 * HID + foff];
                float4 v3 = *(const float4*)&Uin[(size_t)j3 * HID + foff];
                float4 v4 = *(const float4*)&Uin[(size_t)j4 * HID + foff];
                float4 v5 = *(const float4*)&Uin[(size_t)j5 * HID + foff];
                float4 v6 = *(const float4*)&Uin[(size_t)j6 * HID + foff];
                float4 v7 = *(const float4*)&Uin[(size_t)j7 * HID + foff];
                ga.x  += (v0.x + v1.x) + (v2.x + v3.x);
                ga.y  += (v0.y + v1.y) + (v2.y + v3.y);
                ga.z  += (v0.z + v1.z) + (v2.z + v3.z);
                ga.w  += (v0.w + v1.w) + (v2.w + v3.w);
                ga2.x += (v4.x + v5.x) + (v6.x + v7.x);
                ga2.y += (v4.y + v5.y) + (v6.y + v7.y);
                ga2.z += (v4.z + v5.z) + (v6.z + v7.z);
                ga2.w += (v4.w + v5.w) + (v6.w + v7.w);
            }
            for (; e + 2 <= e1; e += 2) {
                int j0 = col[e + 0];
                int j1 = col[e + 1];
                float4 v0 = *(const float4*)&Uin[(size_t)j0 * HID + foff];
                float4 v1 = *(const float4*)&Uin[(size_t)j1 * HID + foff];
                ga.x  += v0.x; ga.y  += v0.y; ga.z  += v0.z; ga.w  += v0.w;
                ga2.x += v1.x; ga2.y += v1.y; ga2.z += v1.z; ga2.w += v1.w;
            }
            if (e < e1) {
                int j = col[e];
                float4 v = *(const float4*)&Uin[(size_t)j * HID + foff];
                ga.x += v.x; ga.y += v.y; ga.z += v.z; ga.w += v.w;
            }
            float d = dis[row];
            ga.x = fmaxf(fmaf(d, ga.x + ga2.x, bb.x), 0.0f);
            ga.y = fmaxf(fmaf(d, ga.y + ga2.y, bb.y), 0.0f);
            ga.z = fmaxf(fmaf(d, ga.z + ga2.z, bb.z), 0.0f);
            ga.w = fmaxf(fmaf(d, ga.w + ga2.w, bb.w), 0.0f);
        }
        *(float4*)&S[(hw * 8 + rr) * ASPITCH + lane * 4] = ga;
    }
    // NO __syncthreads(): B reads only this half-wave's rows (see kernel doc).

    // ---- phase B: S @ W, 4r x 8c, 2-krow ping-pong W prefetch ----
    int tx = tid & 15, ty = tid >> 4;
    int rr0 = ty * 4, c0 = tx * 8;
    const float4* W4 = (const float4*)W;

    float acc[4][8];
    #pragma unroll
    for (int r = 0; r < 4; ++r)
        #pragma unroll
        for (int c = 0; c < 8; ++c) acc[r][c] = 0.0f;

    float4 wa00 = W4[0 * 32 + tx * 2], wa01 = W4[0 * 32 + tx * 2 + 1];
    float4 wa10 = W4[1 * 32 + tx * 2], wa11 = W4[1 * 32 + tx * 2 + 1];
    float4 wb00, wb01, wb10, wb11;

    #pragma unroll 1
    for (int k = 0; k < HID; k += 4) {
        float4 a0 = *(const float4*)&S[(rr0 + 0) * ASPITCH + k];
        float4 a1 = *(const float4*)&S[(rr0 + 1) * ASPITCH + k];
        float4 a2 = *(const float4*)&S[(rr0 + 2) * ASPITCH + k];
        float4 a3 = *(const float4*)&S[(rr0 + 3) * ASPITCH + k];
        wb00 = W4[(k + 2) * 32 + tx * 2]; wb01 = W4[(k + 2) * 32 + tx * 2 + 1];
        wb10 = W4[(k + 3) * 32 + tx * 2]; wb11 = W4[(k + 3) * 32 + tx * 2 + 1];
        FMA8(a0.x, wa00, wa01, 0) FMA8(a1.x, wa00, wa01, 1)
        FMA8(a2.x, wa00, wa01, 2) FMA8(a3.x, wa00, wa01, 3)
        FMA8(a0.y, wa10, wa11, 0) FMA8(a1.y, wa10, wa11, 1)
        FMA8(a2.y, wa10, wa11, 2) FMA8(a3.y, wa10, wa11, 3)
        if (k + 4 < HID) {
            wa00 = W4[(k + 4) * 32 + tx * 2]; wa01 = W4[(k + 4) * 32 + tx * 2 + 1];
            wa10 = W4[(k + 5) * 32 + tx * 2]; wa11 = W4[(k + 5) * 32 + tx * 2 + 1];
        }
        FMA8(a0.z, wb00, wb01, 0) FMA8(a1.z, wb00, wb01, 1)
        FMA8(a2.z, wb00, wb01, 2) FMA8(a3.z, wb00, wb01, 3)
        FMA8(a0.w, wb10, wb11, 0) FMA8(a1.w, wb10, wb11, 1)
        FMA8(a2.w, wb10, wb11, 2) FMA8(a3.w, wb10, wb11, 3)
    }

    int rows = n - r0; if (rows > BM) rows = BM;
    #pragma unroll
    for (int r = 0; r < 4; ++r) {
        int row = rr0 + r;
        if (row < rows) {
            float d = dis[r0 + row];
            float4 o0 = make_float4(acc[r][0] * d, acc[r][1] * d, acc[r][2] * d, acc[r][3] * d);
            float4 o1 = make_float4(acc[r][4] * d, acc[r][5] * d, acc[r][6] * d, acc[r][7] * d);
            *(float4*)&Uout[(size_t)(r0 + row) * HID + c0] = o0;
            *(float4*)&Uout[(size_t)(r0 + row) * HID + c0 + 4] = o1;
        }
    }
}

// Last layer: aggregate + bias + relu + dot with lin_w, all in registers.
// half-wave per node.
__global__ __launch_bounds__(256) void k_agglin(const float* __restrict__ Uin,
                                                const float* __restrict__ b,
                                                const float* __restrict__ dis,
                                                const int* __restrict__ rowptr,
                                                const int* __restrict__ col,
                                                const float* __restrict__ lw,
                                                const float* __restrict__ lb,
                                                float* __restrict__ out, int n) {
    int node = (blockIdx.x * 256 + threadIdx.x) >> 5;
    int lane = threadIdx.x & 31;
    if (node >= n) return;
    size_t foff = (size_t)(lane * 4);
    float4 acc = *(const float4*)&Uin[(size_t)node * HID + foff];
    float4 acc2 = make_float4(0.f, 0.f, 0.f, 0.f);
    int e = rowptr[node], e1 = rowptr[node + 1];
    for (; e + 8 <= e1; e += 8) {
        int j0 = col[e + 0];
        int j1 = col[e + 1];
        int j2 = col[e + 2];
        int j3 = col[e + 3];
        int j4 = col[e + 4];
        int j5 = col[e + 5];
        int j6 = col[e + 6];
        int j7 = col[e + 7];
        float4 v0 = *(const float4*)&Uin[(size_t)j0 * HID + foff];
        float4 v1 = *(const float4*)&Uin[(size_t)j1 * HID + foff];
        float4 v2 = *(const float4*)&Uin[(size_t)j2 * HID + foff];
        float4 v3 = *(const float4*)&Uin[(size_t)j3 * HID + foff];
        float4 v4 = *(const float4*)&Uin[(size_t)j4 * HID + foff];
        float4 v5 = *(const float4*)&Uin[(size_t)j5 * HID + foff];
        float4 v6 = *(const float4*)&Uin[(size_t)j6 * HID + foff];
        float4 v7 = *(const float4*)&Uin[(size_t)j7 * HID + foff];
        acc.x  += (v0.x + v1.x) + (v2.x + v3.x);
        acc.y  += (v0.y + v1.y) + (v2.y + v3.y);
        acc.z  += (v0.z + v1.z) + (v2.z + v3.z);
        acc.w  += (v0.w + v1.w) + (v2.w + v3.w);
        acc2.x += (v4.x + v5.x) + (v6.x + v7.x);
        acc2.y += (v4.y + v5.y) + (v6.y + v7.y);
        acc2.z += (v4.z + v5.z) + (v6.z + v7.z);
        acc2.w += (v4.w + v5.w) + (v6.w + v7.w);
    }
    for (; e + 2 <= e1; e += 2) {
        int j0 = col[e + 0];
        int j1 = col[e + 1];
        float4 v0 = *(const float4*)&Uin[(size_t)j0 * HID + foff];
        float4 v1 = *(const float4*)&Uin[(size_t)j1 * HID + foff];
        acc.x  += v0.x; acc.y  += v0.y; acc.z  += v0.z; acc.w  += v0.w;
        acc2.x += v1.x; acc2.y += v1.y; acc2.z += v1.z; acc2.w += v1.w;
    }
    if (e < e1) {
        int j = col[e];
        float4 v = *(const float4*)&Uin[(size_t)j * HID + foff];
        acc.x += v.x; acc.y += v.y; acc.z += v.z; acc.w += v.w;
    }
    float d = dis[node];
    float4 bb = *(const float4*)&b[lane * 4];
    float4 h;
    h.x = fmaxf(fmaf(d, acc.x + acc2.x, bb.x), 0.0f);
    h.y = fmaxf(fmaf(d, acc.y + acc2.y, bb.y), 0.0f);
    h.z = fmaxf(fmaf(d, acc.z + acc2.z, bb.z), 0.0f);
    h.w = fmaxf(fmaf(d, acc.w + acc2.w, bb.w), 0.0f);
    float4 ww = *(const float4*)&lw[lane * 4];
    float s = h.x * ww.x + h.y * ww.y + h.z * ww.z + h.w * ww.w;
    #pragma unroll
    for (int o = 16; o > 0; o >>= 1) s += __shfl_down(s, o, 64);  // stays within half
    if (lane == 0) out[node] = s + lb[0];
}

// ---------------- launch ----------------

extern "C" void kernel_launch(void* const* d_in, const int* in_sizes, int n_in,
                              void* d_out, int out_size, void* d_ws, size_t ws_size,
                              hipStream_t stream) {
    const float* x     = (const float*)d_in[0];
    const int*   ei    = (const int*)d_in[1];
    const float* Ws    = (const float*)d_in[2];
    const float* bs    = (const float*)d_in[3];
    const float* lin_w = (const float*)d_in[4];
    const float* lin_b = (const float*)d_in[5];
    float* out = (float*)d_out;

    int n = in_sizes[0] / HID;           // 50000
    int E = in_sizes[1] / 2;             // 600000
    int L = in_sizes[2] / (HID * HID);   // 7

    char* ws = (char*)d_ws;
    size_t off = 0;
    auto alloc = [&](size_t bytes) -> void* {
        void* p = ws + off;
        off += (bytes + 255) & ~(size_t)255;
        return p;
    };
    int*   deg     = (int*)alloc((size_t)n * 4);
    int*   cursor  = (int*)alloc((size_t)n * 4);
    int*   rowptr  = (int*)alloc((size_t)(n + 1) * 4);
    int*   partial = (int*)alloc(1024);
    float* dis     = (float*)alloc((size_t)n * 4);
    int*   col     = (int*)alloc((size_t)E * 4);
    float* ubuf0   = (float*)alloc((size_t)n * HID * 4);
    float* ubuf1   = (float*)alloc((size_t)n * HID * 4);
    (void)ws_size;

    hipMemsetAsync(deg, 0, (size_t)n * 4, stream);
    hipMemsetAsync(cursor, 0, (size_t)n * 4, stream);

    int eb = (E + 255) / 256;
    int nb = (n + 255) / 256;
    k_count<<<eb, 256, 0, stream>>>(ei, E, deg);
    k_scan1<<<nb, 256, 0, stream>>>(deg, rowptr, partial, n);
    k_scan2<<<1, 256, 0, stream>>>(partial, nb);
    k_scan3<<<nb, 256, 0, stream>>>(rowptr, partial, n, E);
    k_dis<<<nb, 256, 0, stream>>>(deg, dis, n);
    k_fill<<<eb, 256, 0, stream>>>(ei, E, rowptr, cursor, col);

    int gb = (n + BM - 1) / BM;  // 782
    int hb = (n + 7) / 8;

    // U_0 = dis * (x @ W0)
    k_gemm0<<<gb, 256, 0, stream>>>(x, Ws, dis, ubuf0, n);

    // U_{i+1} = dis * (relu(dis*agg(U_i) + b_i) @ W_{i+1})   for i = 0..L-2
    float* uin = ubuf0;
    float* uout = ubuf1;
    for (int i = 0; i + 1 < L; ++i) {
        k_aggemm<<<gb, 256, 0, stream>>>(uin, Ws + (size_t)(i + 1) * HID * HID,
                                         bs + (size_t)i * HID, dis, rowptr, col,
                                         uout, n);
        float* t = uin; uin = uout; uout = t;
    }

    // out = relu(dis*agg(U_{L-1}) + b_{L-1}) @ lin_w + lin_b
    k_agglin<<<hb, 256, 0, stream>>>(uin, bs + (size_t)(L - 1) * HID, dis,
                                     rowptr, col, lin_w, lin_b, out, n);
}

// Round 14
// 565.372 us; speedup vs baseline: 1.1853x; 1.0892x over previous
//
#include <hip/hip_runtime.h>

#define HID 128
#define BM 64

// ---------------- CSR build ----------------

__global__ __launch_bounds__(256) void k_count(const int* __restrict__ ei, int E,
                                               int* __restrict__ deg) {
    int e = blockIdx.x * 256 + threadIdx.x;
    if (e < E) atomicAdd(&deg[ei[E + e]], 1);   // row 1 of edge_index = dst
}

__global__ __launch_bounds__(256) void k_scan1(const int* __restrict__ deg,
                                               int* __restrict__ rowptr,
                                               int* __restrict__ partial, int n) {
    __shared__ int s[256];
    int tid = threadIdx.x;
    int i = blockIdx.x * 256 + tid;
    int v = (i < n) ? deg[i] : 0;
    s[tid] = v;
    __syncthreads();
    for (int off = 1; off < 256; off <<= 1) {
        int t = (tid >= off) ? s[tid - off] : 0;
        __syncthreads();
        s[tid] += t;
        __syncthreads();
    }
    if (i < n) rowptr[i] = s[tid] - v;           // block-local exclusive
    if (tid == 255) partial[blockIdx.x] = s[255];
}

__global__ __launch_bounds__(256) void k_scan2(int* __restrict__ partial, int nb) {
    __shared__ int s[256];
    int tid = threadIdx.x;
    int v = (tid < nb) ? partial[tid] : 0;
    s[tid] = v;
    __syncthreads();
    for (int off = 1; off < 256; off <<= 1) {
        int t = (tid >= off) ? s[tid - off] : 0;
        __syncthreads();
        s[tid] += t;
        __syncthreads();
    }
    if (tid < nb) partial[tid] = s[tid] - v;     // exclusive over block sums
}

__global__ __launch_bounds__(256) void k_scan3(int* __restrict__ rowptr,
                                               const int* __restrict__ partial,
                                               int n, int E) {
    int i = blockIdx.x * 256 + threadIdx.x;
    if (i < n) rowptr[i] += partial[blockIdx.x];
    if (i == 0) rowptr[n] = E;
}

__global__ __launch_bounds__(256) void k_dis(const int* __restrict__ deg,
                                             float* __restrict__ dis, int n) {
    int i = blockIdx.x * 256 + threadIdx.x;
    if (i < n) dis[i] = 1.0f / sqrtf((float)(deg[i] + 1));  // +1 self-loop
}

__global__ __launch_bounds__(256) void k_fill(const int* __restrict__ ei, int E,
                                              const int* __restrict__ rowptr,
                                              int* __restrict__ cursor,
                                              int* __restrict__ col) {
    int e = blockIdx.x * 256 + threadIdx.x;
    if (e < E) {
        int d = ei[E + e];
        int p = atomicAdd(&cursor[d], 1);
        col[rowptr[d] + p] = ei[e];
    }
}

// ---------------- compute kernels ----------------

// U[i,:] = dis[i] * (A[i,:] @ W) — copy-phase + r8 B body.
// Half-wave hw copies rows 8hw..8hw+7 of A into S (the exact rows its own
// B-phase reads) -> no barrier, no cross-half-wave traffic (r8 privacy arg).
__global__ __launch_bounds__(256, 3) void k_gemm0(const float* __restrict__ A,
                                                  const float* __restrict__ W,
                                                  const float* __restrict__ dis,
                                                  float* __restrict__ T, int n) {
    __shared__ float S[BM * HID];   // 32 KB
    int r0 = blockIdx.x * BM;
    int tid = threadIdx.x;
    int hw = tid >> 5, lane = tid & 31;
    size_t foff = (size_t)(lane * 4);

    // copy 8 rows per half-wave (coalesced float4; zero-fill tail rows)
    #pragma unroll 1
    for (int rr = 0; rr < 8; ++rr) {
        int row = r0 + hw * 8 + rr;
        float4 v = make_float4(0.f, 0.f, 0.f, 0.f);
        if (row < n) v = *(const float4*)&A[(size_t)row * HID + foff];
        *(float4*)&S[(hw * 8 + rr) * HID + lane * 4] = v;
    }
    // NO __syncthreads(): B reads only this half-wave's rows.

    int tx = tid & 31, ty = tid >> 5;
    int rr0 = ty * 8;
    const float4* W4 = (const float4*)W;

    float acc[8][4];
    #pragma unroll
    for (int r = 0; r < 8; ++r) { acc[r][0]=0.f; acc[r][1]=0.f; acc[r][2]=0.f; acc[r][3]=0.f; }

    float4 wa0 = W4[0 * 32 + tx];
    float4 wa1 = W4[1 * 32 + tx];
    float4 wa2 = W4[2 * 32 + tx];
    float4 wa3 = W4[3 * 32 + tx];
    float4 wb0, wb1, wb2, wb3;

    #pragma unroll 1
    for (int k = 0; k < HID; k += 8) {
        wb0 = W4[(k + 4) * 32 + tx];
        wb1 = W4[(k + 5) * 32 + tx];
        wb2 = W4[(k + 6) * 32 + tx];
        wb3 = W4[(k + 7) * 32 + tx];
        #pragma unroll
        for (int r = 0; r < 8; ++r) {
            float4 a = *(const float4*)&S[(rr0 + r) * HID + k];
            acc[r][0] = fmaf(a.x, wa0.x, acc[r][0]);
            acc[r][1] = fmaf(a.x, wa0.y, acc[r][1]);
            acc[r][2] = fmaf(a.x, wa0.z, acc[r][2]);
            acc[r][3] = fmaf(a.x, wa0.w, acc[r][3]);
            acc[r][0] = fmaf(a.y, wa1.x, acc[r][0]);
            acc[r][1] = fmaf(a.y, wa1.y, acc[r][1]);
            acc[r][2] = fmaf(a.y, wa1.z, acc[r][2]);
            acc[r][3] = fmaf(a.y, wa1.w, acc[r][3]);
            acc[r][0] = fmaf(a.z, wa2.x, acc[r][0]);
            acc[r][1] = fmaf(a.z, wa2.y, acc[r][1]);
            acc[r][2] = fmaf(a.z, wa2.z, acc[r][2]);
            acc[r][3] = fmaf(a.z, wa2.w, acc[r][3]);
            acc[r][0] = fmaf(a.w, wa3.x, acc[r][0]);
            acc[r][1] = fmaf(a.w, wa3.y, acc[r][1]);
            acc[r][2] = fmaf(a.w, wa3.z, acc[r][2]);
            acc[r][3] = fmaf(a.w, wa3.w, acc[r][3]);
        }
        if (k + 8 < HID) {
            wa0 = W4[(k + 8)  * 32 + tx];
            wa1 = W4[(k + 9)  * 32 + tx];
            wa2 = W4[(k + 10) * 32 + tx];
            wa3 = W4[(k + 11) * 32 + tx];
        }
        #pragma unroll
        for (int r = 0; r < 8; ++r) {
            float4 a = *(const float4*)&S[(rr0 + r) * HID + k + 4];
            acc[r][0] = fmaf(a.x, wb0.x, acc[r][0]);
            acc[r][1] = fmaf(a.x, wb0.y, acc[r][1]);
            acc[r][2] = fmaf(a.x, wb0.z, acc[r][2]);
            acc[r][3] = fmaf(a.x, wb0.w, acc[r][3]);
            acc[r][0] = fmaf(a.y, wb1.x, acc[r][0]);
            acc[r][1] = fmaf(a.y, wb1.y, acc[r][1]);
            acc[r][2] = fmaf(a.y, wb1.z, acc[r][2]);
            acc[r][3] = fmaf(a.y, wb1.w, acc[r][3]);
            acc[r][0] = fmaf(a.z, wb2.x, acc[r][0]);
            acc[r][1] = fmaf(a.z, wb2.y, acc[r][1]);
            acc[r][2] = fmaf(a.z, wb2.z, acc[r][2]);
            acc[r][3] = fmaf(a.z, wb2.w, acc[r][3]);
            acc[r][0] = fmaf(a.w, wb3.x, acc[r][0]);
            acc[r][1] = fmaf(a.w, wb3.y, acc[r][1]);
            acc[r][2] = fmaf(a.w, wb3.z, acc[r][2]);
            acc[r][3] = fmaf(a.w, wb3.w, acc[r][3]);
        }
    }

    int rows = n - r0; if (rows > BM) rows = BM;
    int c0 = tx * 4;
    #pragma unroll
    for (int r = 0; r < 8; ++r) {
        int row = rr0 + r;
        if (row < rows) {
            float d = dis[r0 + row];
            float4 o = make_float4(acc[r][0] * d, acc[r][1] * d, acc[r][2] * d, acc[r][3] * d);
            *(float4*)&T[(size_t)(r0 + row) * HID + c0] = o;
        }
    }
}

// Fused agg+gemm — EXACT r8 version (best measured: 72.9 us/layer).
// Phase A: half-wave gathers 8 rows (unroll 8/2/1) -> S; phase B: 8r x 4c
// register ping-pong GEMM. No barrier: S rows are half-wave-private.
__global__ __launch_bounds__(256, 3) void k_aggemm(const float* __restrict__ Uin,
                                                   const float* __restrict__ W,
                                                   const float* __restrict__ b,
                                                   const float* __restrict__ dis,
                                                   const int* __restrict__ rowptr,
                                                   const int* __restrict__ col,
                                                   float* __restrict__ Uout, int n) {
    __shared__ float S[BM * HID];   // 32 KB
    int r0 = blockIdx.x * BM;
    int tid = threadIdx.x;
    int hw = tid >> 5, lane = tid & 31;
    size_t foff = (size_t)(lane * 4);
    float4 bb = *(const float4*)&b[lane * 4];

    // ---- phase A: aggregate 8 rows per half-wave ----
    #pragma unroll 1
    for (int rr = 0; rr < 8; ++rr) {
        int row = r0 + hw * 8 + rr;
        float4 acc = make_float4(0.f, 0.f, 0.f, 0.f);
        if (row < n) {
            acc = *(const float4*)&Uin[(size_t)row * HID + foff];   // self (pre-scaled)
            float4 acc2 = make_float4(0.f, 0.f, 0.f, 0.f);
            int e = rowptr[row], e1 = rowptr[row + 1];
            for (; e + 8 <= e1; e += 8) {
                int j0 = col[e + 0];
                int j1 = col[e + 1];
                int j2 = col[e + 2];
                int j3 = col[e + 3];
                int j4 = col[e + 4];
                int j5 = col[e + 5];
                int j6 = col[e + 6];
                int j7 = col[e + 7];
                float4 v0 = *(const float4*)&Uin[(size_t)j0 * HID + foff];
                float4 v1 = *(const float4*)&Uin[(size_t)j1 * HID + foff];
                float4 v2 = *(const float4*)&Uin[(size_t)j2 * HID + foff];
                float4 v3 = *(const float4*)&Uin[(size_t)j3 * HID + foff];
                float4 v4 = *(const float4*)&Uin[(size_t)j4 * HID + foff];
                float4 v5 = *(const float4*)&Uin[(size_t)j5 * HID + foff];
                float4 v6 = *(const float4*)&Uin[(size_t)j6 * HID + foff];
                float4 v7 = *(const float4*)&Uin[(size_t)j7 * HID + foff];
                acc.x  += (v0.x + v1.x) + (v2.x + v3.x);
                acc.y  += (v0.y + v1.y) + (v2.y + v3.y);
                acc.z  += (v0.z + v1.z) + (v2.z + v3.z);
                acc.w  += (v0.w + v1.w) + (v2.w + v3.w);
                acc2.x += (v4.x + v5.x) + (v6.x + v7.x);
                acc2.y += (v4.y + v5.y) + (v6.y + v7.y);
                acc2.z += (v4.z + v5.z) + (v6.z + v7.z);
                acc2.w += (v4.w + v5.w) + (v6.w + v7.w);
            }
            for (; e + 2 <= e1; e += 2) {
                int j0 = col[e + 0];
                int j1 = col[e + 1];
                float4 v0 = *(const float4*)&Uin[(size_t)j0 * HID + foff];
                float4 v1 = *(const float4*)&Uin[(size_t)j1 * HID + foff];
                acc.x  += v0.x; acc.y  += v0.y; acc.z  += v0.z; acc.w  += v0.w;
                acc2.x += v1.x; acc2.y += v1.y; acc2.z += v1.z; acc2.w += v1.w;
            }
            if (e < e1) {
                int j = col[e];
                float4 v = *(const float4*)&Uin[(size_t)j * HID + foff];
                acc.x += v.x; acc.y += v.y; acc.z += v.z; acc.w += v.w;
            }
            float d = dis[row];
            acc.x = fmaxf(fmaf(d, acc.x + acc2.x, bb.x), 0.0f);
            acc.y = fmaxf(fmaf(d, acc.y + acc2.y, bb.y), 0.0f);
            acc.z = fmaxf(fmaf(d, acc.z + acc2.z, bb.z), 0.0f);
            acc.w = fmaxf(fmaf(d, acc.w + acc2.w, bb.w), 0.0f);
        }
        *(float4*)&S[(hw * 8 + rr) * HID + lane * 4] = acc;
    }
    // NO __syncthreads(): S rows are half-wave-private.

    // ---- phase B: S @ W, 8r x 4c, register ping-pong W prefetch ----
    int tx = tid & 31, ty = tid >> 5;
    int rr0 = ty * 8;
    const float4* W4 = (const float4*)W;

    float acc[8][4];
    #pragma unroll
    for (int r = 0; r < 8; ++r) { acc[r][0]=0.f; acc[r][1]=0.f; acc[r][2]=0.f; acc[r][3]=0.f; }

    float4 wa0 = W4[0 * 32 + tx];
    float4 wa1 = W4[1 * 32 + tx];
    float4 wa2 = W4[2 * 32 + tx];
    float4 wa3 = W4[3 * 32 + tx];
    float4 wb0, wb1, wb2, wb3;

    #pragma unroll 1
    for (int k = 0; k < HID; k += 8) {
        wb0 = W4[(k + 4) * 32 + tx];
        wb1 = W4[(k + 5) * 32 + tx];
        wb2 = W4[(k + 6) * 32 + tx];
        wb3 = W4[(k + 7) * 32 + tx];
        #pragma unroll
        for (int r = 0; r < 8; ++r) {
            float4 a = *(const float4*)&S[(rr0 + r) * HID + k];
            acc[r][0] = fmaf(a.x, wa0.x, acc[r][0]);
            acc[r][1] = fmaf(a.x, wa0.y, acc[r][1]);
            acc[r][2] = fmaf(a.x, wa0.z, acc[r][2]);
            acc[r][3] = fmaf(a.x, wa0.w, acc[r][3]);
            acc[r][0] = fmaf(a.y, wa1.x, acc[r][0]);
            acc[r][1] = fmaf(a.y, wa1.y, acc[r][1]);
            acc[r][2] = fmaf(a.y, wa1.z, acc[r][2]);
            acc[r][3] = fmaf(a.y, wa1.w, acc[r][3]);
            acc[r][0] = fmaf(a.z, wa2.x, acc[r][0]);
            acc[r][1] = fmaf(a.z, wa2.y, acc[r][1]);
            acc[r][2] = fmaf(a.z, wa2.z, acc[r][2]);
            acc[r][3] = fmaf(a.z, wa2.w, acc[r][3]);
            acc[r][0] = fmaf(a.w, wa3.x, acc[r][0]);
            acc[r][1] = fmaf(a.w, wa3.y, acc[r][1]);
            acc[r][2] = fmaf(a.w, wa3.z, acc[r][2]);
            acc[r][3] = fmaf(a.w, wa3.w, acc[r][3]);
        }
        if (k + 8 < HID) {
            wa0 = W4[(k + 8)  * 32 + tx];
            wa1 = W4[(k + 9)  * 32 + tx];
            wa2 = W4[(k + 10) * 32 + tx];
            wa3 = W4[(k + 11) * 32 + tx];
        }
        #pragma unroll
        for (int r = 0; r < 8; ++r) {
            float4 a = *(const float4*)&S[(rr0 + r) * HID + k + 4];
            acc[r][0] = fmaf(a.x, wb0.x, acc[r][0]);
            acc[r][1] = fmaf(a.x, wb0.y, acc[r][1]);
            acc[r][2] = fmaf(a.x, wb0.z, acc[r][2]);
            acc[r][3] = fmaf(a.x, wb0.w, acc[r][3]);
            acc[r][0] = fmaf(a.y, wb1.x, acc[r][0]);
            acc[r][1] = fmaf(a.y, wb1.y, acc[r][1]);
            acc[r][2] = fmaf(a.y, wb1.z, acc[r][2]);
            acc[r][3] = fmaf(a.y, wb1.w, acc[r][3]);
            acc[r][0] = fmaf(a.z, wb2.x, acc[r][0]);
            acc[r][1] = fmaf(a.z, wb2.y, acc[r][1]);
            acc[r][2] = fmaf(a.z, wb2.z, acc[r][2]);
            acc[r][3] = fmaf(a.z, wb2.w, acc[r][3]);
            acc[r][0] = fmaf(a.w, wb3.x, acc[r][0]);
            acc[r][1] = fmaf(a.w, wb3.y, acc[r][1]);
            acc[r][2] = fmaf(a.w, wb3.z, acc[r][2]);
            acc[r][3] = fmaf(a.w, wb3.w, acc[r][3]);
        }
    }

    int rows = n - r0; if (rows > BM) rows = BM;
    int c0 = tx * 4;
    #pragma unroll
    for (int r = 0; r < 8; ++r) {
        int row = rr0 + r;
        if (row < rows) {
            float d = dis[r0 + row];
            float4 o = make_float4(acc[r][0] * d, acc[r][1] * d, acc[r][2] * d, acc[r][3] * d);
            *(float4*)&Uout[(size_t)(r0 + row) * HID + c0] = o;
        }
    }
}

// Last layer: aggregate + bias + relu + dot with lin_w, all in registers.
// half-wave per node.
__global__ __launch_bounds__(256) void k_agglin(const float* __restrict__ Uin,
                                                const float* __restrict__ b,
                                                const float* __restrict__ dis,
                                                const int* __restrict__ rowptr,
                                                const int* __restrict__ col,
                                                const float* __restrict__ lw,
                                                const float* __restrict__ lb,
                                                float* __restrict__ out, int n) {
    int node = (blockIdx.x * 256 + threadIdx.x) >> 5;
    int lane = threadIdx.x & 31;
    if (node >= n) return;
    size_t foff = (size_t)(lane * 4);
    float4 acc = *(const float4*)&Uin[(size_t)node * HID + foff];
    float4 acc2 = make_float4(0.f, 0.f, 0.f, 0.f);
    int e = rowptr[node], e1 = rowptr[node + 1];
    for (; e + 8 <= e1; e += 8) {
        int j0 = col[e + 0];
        int j1 = col[e + 1];
        int j2 = col[e + 2];
        int j3 = col[e + 3];
        int j4 = col[e + 4];
        int j5 = col[e + 5];
        int j6 = col[e + 6];
        int j7 = col[e + 7];
        float4 v0 = *(const float4*)&Uin[(size_t)j0 * HID + foff];
        float4 v1 = *(const float4*)&Uin[(size_t)j1 * HID + foff];
        float4 v2 = *(const float4*)&Uin[(size_t)j2 * HID + foff];
        float4 v3 = *(const float4*)&Uin[(size_t)j3 * HID + foff];
        float4 v4 = *(const float4*)&Uin[(size_t)j4 * HID + foff];
        float4 v5 = *(const float4*)&Uin[(size_t)j5 * HID + foff];
        float4 v6 = *(const float4*)&Uin[(size_t)j6 * HID + foff];
        float4 v7 = *(const float4*)&Uin[(size_t)j7 * HID + foff];
        acc.x  += (v0.x + v1.x) + (v2.x + v3.x);
        acc.y  += (v0.y + v1.y) + (v2.y + v3.y);
        acc.z  += (v0.z + v1.z) + (v2.z + v3.z);
        acc.w  += (v0.w + v1.w) + (v2.w + v3.w);
        acc2.x += (v4.x + v5.x) + (v6.x + v7.x);
        acc2.y += (v4.y + v5.y) + (v6.y + v7.y);
        acc2.z += (v4.z + v5.z) + (v6.z + v7.z);
        acc2.w += (v4.w + v5.w) + (v6.w + v7.w);
    }
    for (; e + 2 <= e1; e += 2) {
        int j0 = col[e + 0];
        int j1 = col[e + 1];
        float4 v0 = *(const float4*)&Uin[(size_t)j0 * HID + foff];
        float4 v1 = *(const float4*)&Uin[(size_t)j1 * HID + foff];
        acc.x  += v0.x; acc.y  += v0.y; acc.z  += v0.z; acc.w  += v0.w;
        acc2.x += v1.x; acc2.y += v1.y; acc2.z += v1.z; acc2.w += v1.w;
    }
    if (e < e1) {
        int j = col[e];
        float4 v = *(const float4*)&Uin[(size_t)j * HID + foff];
        acc.x += v.x; acc.y += v.y; acc.z += v.z; acc.w += v.w;
    }
    float d = dis[node];
    float4 bb = *(const float4*)&b[lane * 4];
    float4 h;
    h.x = fmaxf(fmaf(d, acc.x + acc2.x, bb.x), 0.0f);
    h.y = fmaxf(fmaf(d, acc.y + acc2.y, bb.y), 0.0f);
    h.z = fmaxf(fmaf(d, acc.z + acc2.z, bb.z), 0.0f);
    h.w = fmaxf(fmaf(d, acc.w + acc2.w, bb.w), 0.0f);
    float4 ww = *(const float4*)&lw[lane * 4];
    float s = h.x * ww.x + h.y * ww.y + h.z * ww.z + h.w * ww.w;
    #pragma unroll
    for (int o = 16; o > 0; o >>= 1) s += __shfl_down(s, o, 64);  // stays within half
    if (lane == 0) out[node] = s + lb[0];
}

// ---------------- launch ----------------

extern "C" void kernel_launch(void* const* d_in, const int* in_sizes, int n_in,
                              void* d_out, int out_size, void* d_ws, size_t ws_size,
                              hipStream_t stream) {
    const float* x     = (const float*)d_in[0];
    const int*   ei    = (const int*)d_in[1];
    const float* Ws    = (const float*)d_in[2];
    const float* bs    = (const float*)d_in[3];
    const float* lin_w = (const float*)d_in[4];
    const float* lin_b = (const float*)d_in[5];
    float* out = (float*)d_out;

    int n = in_sizes[0] / HID;           // 50000
    int E = in_sizes[1] / 2;             // 600000
    int L = in_sizes[2] / (HID * HID);   // 7

    char* ws = (char*)d_ws;
    size_t off = 0;
    auto alloc = [&](size_t bytes) -> void* {
        void* p = ws + off;
        off += (bytes + 255) & ~(size_t)255;
        return p;
    };
    int*   deg     = (int*)alloc((size_t)n * 4);
    int*   cursor  = (int*)alloc((size_t)n * 4);
    int*   rowptr  = (int*)alloc((size_t)(n + 1) * 4);
    int*   partial = (int*)alloc(1024);
    float* dis     = (float*)alloc((size_t)n * 4);
    int*   col     = (int*)alloc((size_t)E * 4);
    float* ubuf0   = (float*)alloc((size_t)n * HID * 4);
    float* ubuf1   = (float*)alloc((size_t)n * HID * 4);
    (void)ws_size;

    hipMemsetAsync(deg, 0, (size_t)n * 4, stream);
    hipMemsetAsync(cursor, 0, (size_t)n * 4, stream);

    int eb = (E + 255) / 256;
    int nb = (n + 255) / 256;
    k_count<<<eb, 256, 0, stream>>>(ei, E, deg);
    k_scan1<<<nb, 256, 0, stream>>>(deg, rowptr, partial, n);
    k_scan2<<<1, 256, 0, stream>>>(partial, nb);
    k_scan3<<<nb, 256, 0, stream>>>(rowptr, partial, n, E);
    k_dis<<<nb, 256, 0, stream>>>(deg, dis, n);
    k_fill<<<eb, 256, 0, stream>>>(ei, E, rowptr, cursor, col);

    int gb = (n + BM - 1) / BM;  // 782
    int hb = (n + 7) / 8;

    // U_0 = dis * (x @ W0)
    k_gemm0<<<gb, 256, 0, stream>>>(x, Ws, dis, ubuf0, n);

    // U_{i+1} = dis * (relu(dis*agg(U_i) + b_i) @ W_{i+1})   for i = 0..L-2
    float* uin = ubuf0;
    float* uout = ubuf1;
    for (int i = 0; i + 1 < L; ++i) {
        k_aggemm<<<gb, 256, 0, stream>>>(uin, Ws + (size_t)(i + 1) * HID * HID,
                                         bs + (size_t)i * HID, dis, rowptr, col,
                                         uout, n);
        float* t = uin; uin = uout; uout = t;
    }

    // out = relu(dis*agg(U_{L-1}) + b_{L-1}) @ lin_w + lin_b
    k_agglin<<<hb, 256, 0, stream>>>(uin, bs + (size_t)(L - 1) * HID, dis,
                                     rowptr, col, lin_w, lin_b, out, n);
}